// Round 1
// baseline (122.399 us; speedup 1.0000x reference)
//
#include <hip/hip_runtime.h>

// Linear attention (ELU feature map), fused single kernel.
// B=4, N=8, H=8 -> 256 groups, one workgroup per group (one per CU).
// Phase A: KV[d][m] = sum_s K[s,d]*V[s,m], ksum[d] = sum_s K[s,d]
// Phase B: out[l,m] = (sum_d Q[l,d]*KV[d][m]) / (sum_d Q[l,d]*ksum[d] + eps)

constexpr int Bc = 4, Nc = 8, Hc = 8;
constexpr int Lc = 1024, Sc = 1024, Dc = 64, Mc = 64;
constexpr int HD = Hc * Dc;       // 512 floats between consecutive s (or l) rows
constexpr int TA = 32;            // s-rows per phase-A tile
constexpr int NTA = Sc / TA;      // 32 tiles
constexpr int TB = 64;            // l-rows per phase-B tile
constexpr int NTB = Lc / TB;      // 16 tiles
constexpr float EPSF = 1e-6f;

__device__ __forceinline__ float elup1(float x) {
    // elu(x)+1 : x>0 -> x+1 ; else exp(x)
    return x > 0.0f ? x + 1.0f : __expf(x);
}

__global__ void __launch_bounds__(256, 1)
la_fused_kernel(const float* __restrict__ Qg, const float* __restrict__ Kg,
                const float* __restrict__ Vg, const float* __restrict__ Mg,
                float* __restrict__ Og)
{
    __shared__ float lk[TA][Dc];      // 8 KB  staged K tile (elu+mask applied)
    __shared__ float lv[TA][Mc];      // 8 KB  staged V tile
    __shared__ float kvt[Dc][Mc];     // 16 KB KV transposed: kvt[d][m]
    __shared__ float ksm[Dc];         // 256 B
    __shared__ float qt[Dc][TB];      // 16 KB Q tile, transposed + XOR-swizzled

    const int t  = threadIdx.x;
    const int tx = t & 15;            // 0..15
    const int ty = t >> 4;            // 0..15
    const int g  = blockIdx.x;
    const int h  = g & 7;
    const int bn = g >> 3;            // b*N + n
    const int b  = g >> 6;

    // K/V/Q row base for s(or l)=0 of this (b,n,h)
    const size_t rowbase = (size_t)bn * Sc * HD + (size_t)h * Dc;
    const size_t mbase   = (size_t)b * Sc;

    const int d0 = tx * 4;            // this thread's d-columns (phase A)
    const int m0 = ty * 4;            // this thread's m-columns (phase A)
    const int c4 = tx * 4;            // staging column
    const int r0 = ty;                // staging row base

    // ---------------- Phase A: KV state ----------------
    float acc[4][4] = {{0.f,0.f,0.f,0.f},{0.f,0.f,0.f,0.f},{0.f,0.f,0.f,0.f},{0.f,0.f,0.f,0.f}};
    float ks[4] = {0.f, 0.f, 0.f, 0.f};

    float4 kr[2], vr[2];
    float  mr[2];

    auto loadA = [&](int it) {
        const int s0 = it * TA;
        #pragma unroll
        for (int k = 0; k < 2; ++k) {
            const int r = r0 + 16 * k;                       // 0..31
            const size_t off = rowbase + (size_t)(s0 + r) * HD + c4;
            kr[k] = *reinterpret_cast<const float4*>(Kg + off);
            vr[k] = *reinterpret_cast<const float4*>(Vg + off);
            mr[k] = Mg[mbase + s0 + r];
        }
    };
    auto storeA = [&]() {
        #pragma unroll
        for (int k = 0; k < 2; ++k) {
            const int r = r0 + 16 * k;
            float4 kk;
            kk.x = elup1(kr[k].x) * mr[k];
            kk.y = elup1(kr[k].y) * mr[k];
            kk.z = elup1(kr[k].z) * mr[k];
            kk.w = elup1(kr[k].w) * mr[k];
            *reinterpret_cast<float4*>(&lk[r][c4]) = kk;
            *reinterpret_cast<float4*>(&lv[r][c4]) = vr[k];
        }
    };

    loadA(0);
    storeA();
    __syncthreads();
    for (int it = 0; it < NTA; ++it) {
        if (it + 1 < NTA) loadA(it + 1);     // overlap HBM latency with compute
        #pragma unroll 8
        for (int r = 0; r < TA; ++r) {
            const float4 k4 = *reinterpret_cast<const float4*>(&lk[r][d0]);
            const float4 v4 = *reinterpret_cast<const float4*>(&lv[r][m0]);
            const float kk[4] = {k4.x, k4.y, k4.z, k4.w};
            const float vv[4] = {v4.x, v4.y, v4.z, v4.w};
            ks[0] += kk[0]; ks[1] += kk[1]; ks[2] += kk[2]; ks[3] += kk[3];
            #pragma unroll
            for (int i = 0; i < 4; ++i)
                #pragma unroll
                for (int j = 0; j < 4; ++j)
                    acc[i][j] += kk[i] * vv[j];
        }
        __syncthreads();
        if (it + 1 < NTA) storeA();
        __syncthreads();
    }

    // accumulators -> LDS (one-time; bank conflicts here are negligible)
    #pragma unroll
    for (int i = 0; i < 4; ++i) {
        float4 w;
        w.x = acc[i][0]; w.y = acc[i][1]; w.z = acc[i][2]; w.w = acc[i][3];
        *reinterpret_cast<float4*>(&kvt[d0 + i][m0]) = w;
    }
    if (ty == 0) {
        #pragma unroll
        for (int i = 0; i < 4; ++i) ksm[d0 + i] = ks[i];
    }
    __syncthreads();

    // ---------------- Phase B: queries ----------------
    // qt[d][ l ^ ((d>>2 & 7)<<2) ] = elup1(Q[l][d])   (swizzle keeps f4 align)
    float4 qr[4];
    auto loadB = [&](int it) {
        const int l0 = it * TB;
        #pragma unroll
        for (int k = 0; k < 4; ++k) {
            const int r = r0 + 16 * k;                       // 0..63
            const size_t off = rowbase + (size_t)(l0 + r) * HD + c4;
            qr[k] = *reinterpret_cast<const float4*>(Qg + off);
        }
    };
    const int swzw = (tx & 7) << 2;   // swizzle for d in [c4, c4+3] is constant
    auto storeB = [&]() {
        #pragma unroll
        for (int k = 0; k < 4; ++k) {
            const int r = r0 + 16 * k;
            const int lidx = r ^ swzw;
            qt[c4 + 0][lidx] = elup1(qr[k].x);
            qt[c4 + 1][lidx] = elup1(qr[k].y);
            qt[c4 + 2][lidx] = elup1(qr[k].z);
            qt[c4 + 3][lidx] = elup1(qr[k].w);
        }
    };

    loadB(0);
    storeB();
    __syncthreads();
    for (int it = 0; it < NTB; ++it) {
        if (it + 1 < NTB) loadB(it + 1);
        float accB[4][4] = {{0.f,0.f,0.f,0.f},{0.f,0.f,0.f,0.f},{0.f,0.f,0.f,0.f},{0.f,0.f,0.f,0.f}};
        float za[4] = {0.f, 0.f, 0.f, 0.f};
        #pragma unroll 8
        for (int d = 0; d < Dc; ++d) {
            const int swz = ((d >> 2) & 7) << 2;
            const float4 q4  = *reinterpret_cast<const float4*>(&qt[d][(4 * ty) ^ swz]);
            const float4 kv4 = *reinterpret_cast<const float4*>(&kvt[d][4 * tx]);
            const float kd = ksm[d];
            const float qq[4] = {q4.x, q4.y, q4.z, q4.w};
            const float kv[4] = {kv4.x, kv4.y, kv4.z, kv4.w};
            #pragma unroll
            for (int i = 0; i < 4; ++i) {
                za[i] += qq[i] * kd;
                #pragma unroll
                for (int j = 0; j < 4; ++j)
                    accB[i][j] += qq[i] * kv[j];
            }
        }
        // epilogue: normalize + coalesced float4 store
        const int l0 = it * TB;
        const size_t obase = (size_t)bn * Lc * HD + (size_t)h * Mc;
        #pragma unroll
        for (int i = 0; i < 4; ++i) {
            const int l = l0 + 4 * ty + i;
            const float z = 1.0f / (za[i] + EPSF);
            float4 o;
            o.x = accB[i][0] * z; o.y = accB[i][1] * z;
            o.z = accB[i][2] * z; o.w = accB[i][3] * z;
            *reinterpret_cast<float4*>(Og + obase + (size_t)l * HD + 4 * tx) = o;
        }
        __syncthreads();
        if (it + 1 < NTB) storeB();
        __syncthreads();
    }
}

extern "C" void kernel_launch(void* const* d_in, const int* in_sizes, int n_in,
                              void* d_out, int out_size, void* d_ws, size_t ws_size,
                              hipStream_t stream) {
    const float* Qg = (const float*)d_in[0];
    const float* Kg = (const float*)d_in[1];
    const float* Vg = (const float*)d_in[2];
    const float* Mg = (const float*)d_in[3];
    float* Og = (float*)d_out;
    dim3 grid(Bc * Nc * Hc);   // 256 groups
    dim3 block(256);
    hipLaunchKernelGGL(la_fused_kernel, grid, block, 0, stream, Qg, Kg, Vg, Mg, Og);
}

// Round 2
// 108.662 us; speedup vs baseline: 1.1264x; 1.1264x over previous
//
#include <hip/hip_runtime.h>

// Linear attention (ELU feature map).
// Primary path: two kernels through d_ws for 4x occupancy.
//   K1: partial KV[d][m] + ksum[d] over S/4 rows per block (1024 blocks)
//   K2: sum partials -> out[l,m] over L/4 rows per block  (1024 blocks)
// Fallback (ws too small): original fused 256-block kernel.

constexpr int Bc = 4, Nc = 8, Hc = 8;
constexpr int Lc = 1024, Sc = 1024, Dc = 64, Mc = 64;
constexpr int HD = Hc * Dc;            // 512 floats between consecutive rows
constexpr int GROUPS = Bc * Nc * Hc;   // 256
constexpr int SPLITS = 4;              // s-splits (kernel 1)
constexpr int SROWS = Sc / SPLITS;     // 256
constexpr int LSPLITS = 4;             // l-splits (kernel 2)
constexpr int LROWS = Lc / LSPLITS;    // 256
constexpr int PARTIAL = Dc * Mc + Dc;  // 4160 floats per partial
constexpr float EPSF = 1e-6f;

__device__ __forceinline__ float elup1(float x) {
    return x > 0.0f ? x + 1.0f : __expf(x);
}

// ---------------- Kernel 1: partial KV state ----------------
__global__ void __launch_bounds__(256, 4)
la_kv_partial(const float* __restrict__ Kg, const float* __restrict__ Vg,
              const float* __restrict__ Mg, float* __restrict__ ws)
{
    __shared__ float lk[32][Dc];   // 8 KB
    __shared__ float lv[32][Mc];   // 8 KB

    const int t  = threadIdx.x;
    const int tx = t & 15;
    const int ty = t >> 4;
    const int g  = blockIdx.y;     // group (b*N+n)*H + h
    const int sp = blockIdx.x;     // s-split
    const int h  = g & 7;
    const int bn = g >> 3;
    const int b  = g >> 6;

    const size_t rowbase = (size_t)bn * Sc * HD + (size_t)h * Dc;
    const size_t mbase   = (size_t)b * Sc;
    const int    sbase   = sp * SROWS;

    const int d0 = tx * 4, m0 = ty * 4, c4 = tx * 4, r0 = ty;

    float acc[4][4] = {{0.f,0.f,0.f,0.f},{0.f,0.f,0.f,0.f},{0.f,0.f,0.f,0.f},{0.f,0.f,0.f,0.f}};
    float ks[4] = {0.f, 0.f, 0.f, 0.f};
    float4 kr[2], vr[2];
    float  mr[2];

    auto loadA = [&](int it) {
        const int s0 = sbase + it * 32;
        #pragma unroll
        for (int k = 0; k < 2; ++k) {
            const int r = r0 + 16 * k;
            const size_t off = rowbase + (size_t)(s0 + r) * HD + c4;
            kr[k] = *reinterpret_cast<const float4*>(Kg + off);
            vr[k] = *reinterpret_cast<const float4*>(Vg + off);
            mr[k] = Mg[mbase + s0 + r];
        }
    };
    auto storeA = [&]() {
        #pragma unroll
        for (int k = 0; k < 2; ++k) {
            const int r = r0 + 16 * k;
            float4 kk;
            kk.x = elup1(kr[k].x) * mr[k];
            kk.y = elup1(kr[k].y) * mr[k];
            kk.z = elup1(kr[k].z) * mr[k];
            kk.w = elup1(kr[k].w) * mr[k];
            *reinterpret_cast<float4*>(&lk[r][c4]) = kk;
            *reinterpret_cast<float4*>(&lv[r][c4]) = vr[k];
        }
    };

    constexpr int NT = SROWS / 32;   // 8 tiles
    loadA(0);
    storeA();
    __syncthreads();
    for (int it = 0; it < NT; ++it) {
        if (it + 1 < NT) loadA(it + 1);
        #pragma unroll 8
        for (int r = 0; r < 32; ++r) {
            const float4 k4 = *reinterpret_cast<const float4*>(&lk[r][d0]);
            const float4 v4 = *reinterpret_cast<const float4*>(&lv[r][m0]);
            const float kk[4] = {k4.x, k4.y, k4.z, k4.w};
            const float vv[4] = {v4.x, v4.y, v4.z, v4.w};
            ks[0] += kk[0]; ks[1] += kk[1]; ks[2] += kk[2]; ks[3] += kk[3];
            #pragma unroll
            for (int i = 0; i < 4; ++i)
                #pragma unroll
                for (int j = 0; j < 4; ++j)
                    acc[i][j] += kk[i] * vv[j];
        }
        __syncthreads();
        if (it + 1 < NT) storeA();
        __syncthreads();
    }

    float* out = ws + (size_t)(g * SPLITS + sp) * PARTIAL;
    #pragma unroll
    for (int i = 0; i < 4; ++i) {
        float4 w;
        w.x = acc[i][0]; w.y = acc[i][1]; w.z = acc[i][2]; w.w = acc[i][3];
        *reinterpret_cast<float4*>(out + (d0 + i) * Mc + m0) = w;
    }
    if (ty == 0) {
        #pragma unroll
        for (int i = 0; i < 4; ++i) out[Dc * Mc + d0 + i] = ks[i];
    }
}

// ---------------- Kernel 2: reduce partials + queries ----------------
__global__ void __launch_bounds__(256, 4)
la_out(const float* __restrict__ Qg, const float* __restrict__ ws,
       float* __restrict__ Og)
{
    __shared__ float kvt[Dc][Mc];  // 16 KB
    __shared__ float ksm[Dc];
    __shared__ float qt[Dc][64];   // 16 KB, transposed + swizzled

    const int t  = threadIdx.x;
    const int tx = t & 15;
    const int ty = t >> 4;
    const int g  = blockIdx.y;
    const int ls = blockIdx.x;
    const int h  = g & 7;
    const int bn = g >> 3;

    const size_t rowbase = (size_t)bn * Lc * HD + (size_t)h * Dc;
    const float* pw = ws + (size_t)g * SPLITS * PARTIAL;

    // sum the 4 partials into LDS (coalesced float4 reads)
    for (int idx = t * 4; idx < Dc * Mc; idx += 1024) {
        float4 s = {0.f, 0.f, 0.f, 0.f};
        #pragma unroll
        for (int sp = 0; sp < SPLITS; ++sp) {
            const float4 p = *reinterpret_cast<const float4*>(pw + sp * PARTIAL + idx);
            s.x += p.x; s.y += p.y; s.z += p.z; s.w += p.w;
        }
        *reinterpret_cast<float4*>(&kvt[0][0] + idx) = s;
    }
    if (t < Dc) {
        float s = 0.f;
        #pragma unroll
        for (int sp = 0; sp < SPLITS; ++sp) s += pw[sp * PARTIAL + Dc * Mc + t];
        ksm[t] = s;
    }

    const int lbase = ls * LROWS;
    const int c4 = tx * 4, r0 = ty;
    float4 qr[4];
    auto loadB = [&](int it) {
        const int l0 = lbase + it * 64;
        #pragma unroll
        for (int k = 0; k < 4; ++k) {
            const int r = r0 + 16 * k;
            const size_t off = rowbase + (size_t)(l0 + r) * HD + c4;
            qr[k] = *reinterpret_cast<const float4*>(Qg + off);
        }
    };
    const int swzw = (tx & 7) << 2;
    auto storeB = [&]() {
        #pragma unroll
        for (int k = 0; k < 4; ++k) {
            const int r = r0 + 16 * k;
            const int lidx = r ^ swzw;
            qt[c4 + 0][lidx] = elup1(qr[k].x);
            qt[c4 + 1][lidx] = elup1(qr[k].y);
            qt[c4 + 2][lidx] = elup1(qr[k].z);
            qt[c4 + 3][lidx] = elup1(qr[k].w);
        }
    };

    constexpr int NT = LROWS / 64;   // 4 tiles
    loadB(0);
    storeB();
    __syncthreads();                  // covers kvt/ksm fill + qt tile 0
    for (int it = 0; it < NT; ++it) {
        if (it + 1 < NT) loadB(it + 1);
        float accB[4][4] = {{0.f,0.f,0.f,0.f},{0.f,0.f,0.f,0.f},{0.f,0.f,0.f,0.f},{0.f,0.f,0.f,0.f}};
        float za[4] = {0.f, 0.f, 0.f, 0.f};
        #pragma unroll 8
        for (int d = 0; d < Dc; ++d) {
            const int swz = ((d >> 2) & 7) << 2;
            const float4 q4  = *reinterpret_cast<const float4*>(&qt[d][(4 * ty) ^ swz]);
            const float4 kv4 = *reinterpret_cast<const float4*>(&kvt[d][4 * tx]);
            const float kd = ksm[d];
            const float qq[4] = {q4.x, q4.y, q4.z, q4.w};
            const float kv[4] = {kv4.x, kv4.y, kv4.z, kv4.w};
            #pragma unroll
            for (int i = 0; i < 4; ++i) {
                za[i] += qq[i] * kd;
                #pragma unroll
                for (int j = 0; j < 4; ++j)
                    accB[i][j] += qq[i] * kv[j];
            }
        }
        const int l0 = lbase + it * 64;
        const size_t obase = (size_t)bn * Lc * HD + (size_t)h * Mc;
        #pragma unroll
        for (int i = 0; i < 4; ++i) {
            const int l = l0 + 4 * ty + i;
            const float z = 1.0f / (za[i] + EPSF);
            float4 o;
            o.x = accB[i][0] * z; o.y = accB[i][1] * z;
            o.z = accB[i][2] * z; o.w = accB[i][3] * z;
            *reinterpret_cast<float4*>(Og + obase + (size_t)l * HD + 4 * tx) = o;
        }
        __syncthreads();
        if (it + 1 < NT) storeB();
        __syncthreads();
    }
}

// ---------------- Fallback: original fused kernel ----------------
__global__ void __launch_bounds__(256, 1)
la_fused_kernel(const float* __restrict__ Qg, const float* __restrict__ Kg,
                const float* __restrict__ Vg, const float* __restrict__ Mg,
                float* __restrict__ Og)
{
    __shared__ float lk[32][Dc];
    __shared__ float lv[32][Mc];
    __shared__ float kvt[Dc][Mc];
    __shared__ float ksm[Dc];
    __shared__ float qt[Dc][64];

    const int t  = threadIdx.x;
    const int tx = t & 15;
    const int ty = t >> 4;
    const int g  = blockIdx.x;
    const int h  = g & 7;
    const int bn = g >> 3;
    const int b  = g >> 6;

    const size_t rowbase = (size_t)bn * Sc * HD + (size_t)h * Dc;
    const size_t mbase   = (size_t)b * Sc;

    const int d0 = tx * 4, m0 = ty * 4, c4 = tx * 4, r0 = ty;

    float acc[4][4] = {{0.f,0.f,0.f,0.f},{0.f,0.f,0.f,0.f},{0.f,0.f,0.f,0.f},{0.f,0.f,0.f,0.f}};
    float ks[4] = {0.f, 0.f, 0.f, 0.f};
    float4 kr[2], vr[2];
    float  mr[2];

    auto loadA = [&](int it) {
        const int s0 = it * 32;
        #pragma unroll
        for (int k = 0; k < 2; ++k) {
            const int r = r0 + 16 * k;
            const size_t off = rowbase + (size_t)(s0 + r) * HD + c4;
            kr[k] = *reinterpret_cast<const float4*>(Kg + off);
            vr[k] = *reinterpret_cast<const float4*>(Vg + off);
            mr[k] = Mg[mbase + s0 + r];
        }
    };
    auto storeA = [&]() {
        #pragma unroll
        for (int k = 0; k < 2; ++k) {
            const int r = r0 + 16 * k;
            float4 kk;
            kk.x = elup1(kr[k].x) * mr[k];
            kk.y = elup1(kr[k].y) * mr[k];
            kk.z = elup1(kr[k].z) * mr[k];
            kk.w = elup1(kr[k].w) * mr[k];
            *reinterpret_cast<float4*>(&lk[r][c4]) = kk;
            *reinterpret_cast<float4*>(&lv[r][c4]) = vr[k];
        }
    };

    loadA(0);
    storeA();
    __syncthreads();
    for (int it = 0; it < Sc / 32; ++it) {
        if (it + 1 < Sc / 32) loadA(it + 1);
        #pragma unroll 8
        for (int r = 0; r < 32; ++r) {
            const float4 k4 = *reinterpret_cast<const float4*>(&lk[r][d0]);
            const float4 v4 = *reinterpret_cast<const float4*>(&lv[r][m0]);
            const float kk[4] = {k4.x, k4.y, k4.z, k4.w};
            const float vv[4] = {v4.x, v4.y, v4.z, v4.w};
            ks[0] += kk[0]; ks[1] += kk[1]; ks[2] += kk[2]; ks[3] += kk[3];
            #pragma unroll
            for (int i = 0; i < 4; ++i)
                #pragma unroll
                for (int j = 0; j < 4; ++j)
                    acc[i][j] += kk[i] * vv[j];
        }
        __syncthreads();
        if (it + 1 < Sc / 32) storeA();
        __syncthreads();
    }

    #pragma unroll
    for (int i = 0; i < 4; ++i) {
        float4 w;
        w.x = acc[i][0]; w.y = acc[i][1]; w.z = acc[i][2]; w.w = acc[i][3];
        *reinterpret_cast<float4*>(&kvt[d0 + i][m0]) = w;
    }
    if (ty == 0) {
        #pragma unroll
        for (int i = 0; i < 4; ++i) ksm[d0 + i] = ks[i];
    }
    __syncthreads();

    float4 qr[4];
    auto loadB = [&](int it) {
        const int l0 = it * 64;
        #pragma unroll
        for (int k = 0; k < 4; ++k) {
            const int r = r0 + 16 * k;
            const size_t off = rowbase + (size_t)(l0 + r) * HD + c4;
            qr[k] = *reinterpret_cast<const float4*>(Qg + off);
        }
    };
    const int swzw = (tx & 7) << 2;
    auto storeB = [&]() {
        #pragma unroll
        for (int k = 0; k < 4; ++k) {
            const int r = r0 + 16 * k;
            const int lidx = r ^ swzw;
            qt[c4 + 0][lidx] = elup1(qr[k].x);
            qt[c4 + 1][lidx] = elup1(qr[k].y);
            qt[c4 + 2][lidx] = elup1(qr[k].z);
            qt[c4 + 3][lidx] = elup1(qr[k].w);
        }
    };

    loadB(0);
    storeB();
    __syncthreads();
    for (int it = 0; it < Lc / 64; ++it) {
        if (it + 1 < Lc / 64) loadB(it + 1);
        float accB[4][4] = {{0.f,0.f,0.f,0.f},{0.f,0.f,0.f,0.f},{0.f,0.f,0.f,0.f},{0.f,0.f,0.f,0.f}};
        float za[4] = {0.f, 0.f, 0.f, 0.f};
        #pragma unroll 8
        for (int d = 0; d < Dc; ++d) {
            const int swz = ((d >> 2) & 7) << 2;
            const float4 q4  = *reinterpret_cast<const float4*>(&qt[d][(4 * ty) ^ swz]);
            const float4 kv4 = *reinterpret_cast<const float4*>(&kvt[d][4 * tx]);
            const float kd = ksm[d];
            const float qq[4] = {q4.x, q4.y, q4.z, q4.w};
            const float kv[4] = {kv4.x, kv4.y, kv4.z, kv4.w};
            #pragma unroll
            for (int i = 0; i < 4; ++i) {
                za[i] += qq[i] * kd;
                #pragma unroll
                for (int j = 0; j < 4; ++j)
                    accB[i][j] += qq[i] * kv[j];
            }
        }
        const int l0 = it * 64;
        const size_t obase = (size_t)bn * Lc * HD + (size_t)h * Mc;
        #pragma unroll
        for (int i = 0; i < 4; ++i) {
            const int l = l0 + 4 * ty + i;
            const float z = 1.0f / (za[i] + EPSF);
            float4 o;
            o.x = accB[i][0] * z; o.y = accB[i][1] * z;
            o.z = accB[i][2] * z; o.w = accB[i][3] * z;
            *reinterpret_cast<float4*>(Og + obase + (size_t)l * HD + 4 * tx) = o;
        }
        __syncthreads();
        if (it + 1 < Lc / 64) storeB();
        __syncthreads();
    }
}

extern "C" void kernel_launch(void* const* d_in, const int* in_sizes, int n_in,
                              void* d_out, int out_size, void* d_ws, size_t ws_size,
                              hipStream_t stream) {
    const float* Qg = (const float*)d_in[0];
    const float* Kg = (const float*)d_in[1];
    const float* Vg = (const float*)d_in[2];
    const float* Mg = (const float*)d_in[3];
    float* Og = (float*)d_out;

    const size_t need = (size_t)GROUPS * SPLITS * PARTIAL * sizeof(float);
    if (ws_size >= need) {
        float* ws = (float*)d_ws;
        hipLaunchKernelGGL(la_kv_partial, dim3(SPLITS, GROUPS), dim3(256), 0, stream,
                           Kg, Vg, Mg, ws);
        hipLaunchKernelGGL(la_out, dim3(LSPLITS, GROUPS), dim3(256), 0, stream,
                           Qg, ws, Og);
    } else {
        hipLaunchKernelGGL(la_fused_kernel, dim3(GROUPS), dim3(256), 0, stream,
                           Qg, Kg, Vg, Mg, Og);
    }
}

// Round 4
// 67.928 us; speedup vs baseline: 1.8019x; 1.5997x over previous
//
#include <hip/hip_runtime.h>
#include <hip/hip_bf16.h>

// Linear attention (ELU feature map) via bf16 MFMA.
//   K1: partial KV[d][m] (+ksum) per s-split, MFMA K^T*V   (1024 blocks)
//   K2: sum partials, O = phiQ*KV with Z via MFMA          (1024 blocks)
// Fallback (ws too small): fp32 fused kernel (R1, verified).
// R3 fix: K2's LDS tiles (kvm, qb) have inner dim 64 (d), not 32 (s) —
// they need their own pad constant PADD=68. R2 overflowed rows (PADS=36).

constexpr int Bc = 4, Nc = 8, Hc = 8;
constexpr int Lc = 1024, Sc = 1024, Dc = 64, Mc = 64;
constexpr int HD = Hc * Dc;            // 512 floats between consecutive rows
constexpr int GROUPS = Bc * Nc * Hc;   // 256
constexpr int SPLITS = 4;
constexpr int SROWS = Sc / SPLITS;     // 256
constexpr int LSPLITS = 4;
constexpr int LROWS = Lc / LSPLITS;    // 256
constexpr int PARTIAL = Dc * Mc + Dc;  // 4160 floats per partial
constexpr int NTS = SROWS / 32;        // 8 K-steps (32 s each)
constexpr int NTL = LROWS / 64;        // 4 l-tiles (64 rows each)
constexpr int PADS = 36;               // K1 inner dim: 32 s + 4 pad (bf16)
constexpr int PADD = 68;               // K2 inner dim: 64 d + 4 pad (bf16)
constexpr float EPSF = 1e-6f;

typedef __attribute__((ext_vector_type(8))) __bf16 bf16x8;
typedef __attribute__((ext_vector_type(4))) float f32x4;

__device__ __forceinline__ float elup1(float x) {
    return x > 0.0f ? x + 1.0f : __expf(x);
}
__device__ __forceinline__ unsigned short f2bf(float f) {
    unsigned u = __builtin_bit_cast(unsigned, f);
    u += 0x7fffu + ((u >> 16) & 1u);          // round-to-nearest-even
    return (unsigned short)(u >> 16);
}
__device__ __forceinline__ unsigned packbf(float lo, float hi) {
    return (unsigned)f2bf(lo) | ((unsigned)f2bf(hi) << 16);
}

// ---------------- Kernel 1: partial KV via MFMA ----------------
__global__ void __launch_bounds__(256, 4)
la_kv_mfma(const float* __restrict__ Kg, const float* __restrict__ Vg,
           const float* __restrict__ Mg, float* __restrict__ ws)
{
    __shared__ unsigned short kt[Dc][PADS];   // kt[d][s] bf16 (phi*mask applied)
    __shared__ unsigned short vt[Mc][PADS];   // vt[m][s] bf16
    __shared__ float ksred[16][64];

    const int t    = threadIdx.x;
    const int tx   = t & 15;
    const int tyq  = t >> 4;       // 0..15
    const int lane = t & 63;
    const int w    = t >> 6;       // wave 0..3
    const int g    = blockIdx.y;
    const int sp   = blockIdx.x;
    const int h    = g & 7;
    const int bn   = g >> 3;
    const int b    = g >> 6;

    const size_t rowbase = (size_t)bn * Sc * HD + (size_t)h * Dc;
    const size_t mbase   = (size_t)b * Sc;
    const int    sbase   = sp * SROWS;

    float4 kr0, kr1, vr0, vr1;
    float  mr0, mr1;
    float  ksp[4] = {0.f, 0.f, 0.f, 0.f};

    auto loadA = [&](int it) {
        const int s0 = sbase + it * 32 + 2 * tyq;
        const size_t off = rowbase + (size_t)s0 * HD + 4 * tx;
        kr0 = *reinterpret_cast<const float4*>(Kg + off);
        kr1 = *reinterpret_cast<const float4*>(Kg + off + HD);
        vr0 = *reinterpret_cast<const float4*>(Vg + off);
        vr1 = *reinterpret_cast<const float4*>(Vg + off + HD);
        mr0 = Mg[mbase + s0];
        mr1 = Mg[mbase + s0 + 1];
    };
    auto storeA = [&]() {
        const float k0[4] = {kr0.x, kr0.y, kr0.z, kr0.w};
        const float k1[4] = {kr1.x, kr1.y, kr1.z, kr1.w};
        const float v0[4] = {vr0.x, vr0.y, vr0.z, vr0.w};
        const float v1[4] = {vr1.x, vr1.y, vr1.z, vr1.w};
        #pragma unroll
        for (int i = 0; i < 4; ++i) {
            const float a0 = elup1(k0[i]) * mr0;
            const float a1 = elup1(k1[i]) * mr1;
            ksp[i] += a0 + a1;
            *reinterpret_cast<unsigned*>(&kt[4 * tx + i][2 * tyq]) = packbf(a0, a1);
            *reinterpret_cast<unsigned*>(&vt[4 * tx + i][2 * tyq]) = packbf(v0[i], v1[i]);
        }
    };

    f32x4 acc[4];
    #pragma unroll
    for (int ms = 0; ms < 4; ++ms) acc[ms] = (f32x4){0.f, 0.f, 0.f, 0.f};

    const int fcol = 8 * (lane >> 4);     // k-group start (bf16 elems)
    const int frow = lane & 15;

    loadA(0);
    storeA();
    __syncthreads();
    for (int it = 0; it < NTS; ++it) {
        if (it + 1 < NTS) loadA(it + 1);
        union { bf16x8 v; uint2 u[2]; } fa;
        {
            const uint2* p = reinterpret_cast<const uint2*>(&kt[16 * w + frow][fcol]);
            fa.u[0] = p[0]; fa.u[1] = p[1];
        }
        #pragma unroll
        for (int ms = 0; ms < 4; ++ms) {
            union { bf16x8 v; uint2 u[2]; } fb;
            const uint2* p = reinterpret_cast<const uint2*>(&vt[16 * ms + frow][fcol]);
            fb.u[0] = p[0]; fb.u[1] = p[1];
            acc[ms] = __builtin_amdgcn_mfma_f32_16x16x32_bf16(fa.v, fb.v, acc[ms], 0, 0, 0);
        }
        __syncthreads();
        if (it + 1 < NTS) storeA();
        __syncthreads();
    }

    float* outp = ws + (size_t)(g * SPLITS + sp) * PARTIAL;
    #pragma unroll
    for (int ms = 0; ms < 4; ++ms)
        #pragma unroll
        for (int r = 0; r < 4; ++r)
            outp[(16 * w + 4 * (lane >> 4) + r) * Mc + 16 * ms + frow] = acc[ms][r];

    #pragma unroll
    for (int i = 0; i < 4; ++i) ksred[tyq][4 * tx + i] = ksp[i];
    __syncthreads();
    if (t < 64) {
        float s = 0.f;
        #pragma unroll
        for (int j = 0; j < 16; ++j) s += ksred[j][t];
        outp[Dc * Mc + t] = s;
    }
}

// ---------------- Kernel 2: output via MFMA ----------------
__global__ void __launch_bounds__(256, 4)
la_out_mfma(const float* __restrict__ Qg, const float* __restrict__ ws,
            float* __restrict__ Og)
{
    __shared__ unsigned short kvm[Mc][PADD];  // kvm[m][d] bf16 (summed partials)
    __shared__ unsigned short ksb[64];        // ksum bf16
    __shared__ unsigned short qb[64][PADD];   // qb[l][d] bf16 (phi applied)

    const int t    = threadIdx.x;
    const int tx   = t & 15;
    const int tyq  = t >> 4;
    const int lane = t & 63;
    const int w    = t >> 6;
    const int g    = blockIdx.y;
    const int ls   = blockIdx.x;
    const int h    = g & 7;
    const int bn   = g >> 3;

    const size_t rowbase = (size_t)bn * Lc * HD + (size_t)h * Dc;
    const float* pw = ws + (size_t)g * SPLITS * PARTIAL;
    const int lbase = ls * LROWS;

    float4 qr[4];
    auto loadB = [&](int it) {
        const int l0 = lbase + it * 64 + 4 * tyq;
        #pragma unroll
        for (int j = 0; j < 4; ++j)
            qr[j] = *reinterpret_cast<const float4*>(Qg + rowbase + (size_t)(l0 + j) * HD + 4 * tx);
    };
    auto storeB = [&]() {
        #pragma unroll
        for (int j = 0; j < 4; ++j) {
            const int r = 4 * tyq + j;
            const float q[4] = {qr[j].x, qr[j].y, qr[j].z, qr[j].w};
            uint2 pk;
            pk.x = packbf(elup1(q[0]), elup1(q[1]));
            pk.y = packbf(elup1(q[2]), elup1(q[3]));
            *reinterpret_cast<uint2*>(&qb[r][4 * tx]) = pk;
        }
    };

    loadB(0);
    // sum the 4 partials; transpose into kvm[m][d] (one-time)
    #pragma unroll
    for (int e = 0; e < 16; ++e) {
        const int idx = t + 256 * e;
        const float s = pw[idx] + pw[PARTIAL + idx] + pw[2 * PARTIAL + idx] + pw[3 * PARTIAL + idx];
        kvm[idx & 63][idx >> 6] = f2bf(s);
    }
    if (t < 64) {
        const float s = pw[Dc * Mc + t] + pw[PARTIAL + Dc * Mc + t]
                      + pw[2 * PARTIAL + Dc * Mc + t] + pw[3 * PARTIAL + Dc * Mc + t];
        ksb[t] = f2bf(s);
    }
    storeB();
    __syncthreads();

    const int fcol = 8 * (lane >> 4);
    const int frow = lane & 15;

    // hoist B-operand fragments (KV + ksum) into registers
    bf16x8 bkv[2][4], bks[2];
    #pragma unroll
    for (int ks = 0; ks < 2; ++ks) {
        #pragma unroll
        for (int ms = 0; ms < 4; ++ms) {
            union { bf16x8 v; uint2 u[2]; } f;
            const uint2* p = reinterpret_cast<const uint2*>(&kvm[16 * ms + frow][32 * ks + fcol]);
            f.u[0] = p[0]; f.u[1] = p[1];
            bkv[ks][ms] = f.v;
        }
        union { bf16x8 v; uint2 u[2]; } fz;
        const uint2* p = reinterpret_cast<const uint2*>(&ksb[32 * ks + fcol]);
        fz.u[0] = p[0]; fz.u[1] = p[1];
        bks[ks] = fz.v;
    }

    const size_t obase = (size_t)bn * Lc * HD + (size_t)h * Mc;
    for (int it = 0; it < NTL; ++it) {
        if (it + 1 < NTL) loadB(it + 1);
        union { bf16x8 v; uint2 u[2]; } fa0, fa1;
        {
            const uint2* p0 = reinterpret_cast<const uint2*>(&qb[16 * w + frow][fcol]);
            fa0.u[0] = p0[0]; fa0.u[1] = p0[1];
            const uint2* p1 = reinterpret_cast<const uint2*>(&qb[16 * w + frow][32 + fcol]);
            fa1.u[0] = p1[0]; fa1.u[1] = p1[1];
        }
        f32x4 acc[4], accz;
        #pragma unroll
        for (int ms = 0; ms < 4; ++ms) acc[ms] = (f32x4){0.f, 0.f, 0.f, 0.f};
        accz = (f32x4){0.f, 0.f, 0.f, 0.f};
        #pragma unroll
        for (int ms = 0; ms < 4; ++ms) {
            acc[ms] = __builtin_amdgcn_mfma_f32_16x16x32_bf16(fa0.v, bkv[0][ms], acc[ms], 0, 0, 0);
            acc[ms] = __builtin_amdgcn_mfma_f32_16x16x32_bf16(fa1.v, bkv[1][ms], acc[ms], 0, 0, 0);
        }
        accz = __builtin_amdgcn_mfma_f32_16x16x32_bf16(fa0.v, bks[0], accz, 0, 0, 0);
        accz = __builtin_amdgcn_mfma_f32_16x16x32_bf16(fa1.v, bks[1], accz, 0, 0, 0);

        const int lt = lbase + it * 64 + 16 * w + 4 * (lane >> 4);
        #pragma unroll
        for (int r = 0; r < 4; ++r) {
            const float z = 1.0f / (accz[r] + EPSF);
            const size_t ro = obase + (size_t)(lt + r) * HD + frow;
            #pragma unroll
            for (int ms = 0; ms < 4; ++ms)
                Og[ro + 16 * ms] = acc[ms][r] * z;
        }
        __syncthreads();
        if (it + 1 < NTL) storeB();
        __syncthreads();
    }
}

// ---------------- Fallback: fp32 fused kernel (verified R1) ----------------
__global__ void __launch_bounds__(256, 1)
la_fused_kernel(const float* __restrict__ Qg, const float* __restrict__ Kg,
                const float* __restrict__ Vg, const float* __restrict__ Mg,
                float* __restrict__ Og)
{
    __shared__ float lk[32][Dc];
    __shared__ float lv[32][Mc];
    __shared__ float kvt[Dc][Mc];
    __shared__ float ksm[Dc];
    __shared__ float qt[Dc][64];

    const int t  = threadIdx.x;
    const int tx = t & 15;
    const int ty = t >> 4;
    const int g  = blockIdx.x;
    const int h  = g & 7;
    const int bn = g >> 3;
    const int b  = g >> 6;

    const size_t rowbase = (size_t)bn * Sc * HD + (size_t)h * Dc;
    const size_t mbase   = (size_t)b * Sc;

    const int d0 = tx * 4, m0 = ty * 4, c4 = tx * 4, r0 = ty;

    float acc[4][4] = {{0.f,0.f,0.f,0.f},{0.f,0.f,0.f,0.f},{0.f,0.f,0.f,0.f},{0.f,0.f,0.f,0.f}};
    float ks[4] = {0.f, 0.f, 0.f, 0.f};
    float4 kr[2], vr[2];
    float  mr[2];

    auto loadA = [&](int it) {
        const int s0 = it * 32;
        #pragma unroll
        for (int k = 0; k < 2; ++k) {
            const int r = r0 + 16 * k;
            const size_t off = rowbase + (size_t)(s0 + r) * HD + c4;
            kr[k] = *reinterpret_cast<const float4*>(Kg + off);
            vr[k] = *reinterpret_cast<const float4*>(Vg + off);
            mr[k] = Mg[mbase + s0 + r];
        }
    };
    auto storeA = [&]() {
        #pragma unroll
        for (int k = 0; k < 2; ++k) {
            const int r = r0 + 16 * k;
            float4 kk;
            kk.x = elup1(kr[k].x) * mr[k];
            kk.y = elup1(kr[k].y) * mr[k];
            kk.z = elup1(kr[k].z) * mr[k];
            kk.w = elup1(kr[k].w) * mr[k];
            *reinterpret_cast<float4*>(&lk[r][c4]) = kk;
            *reinterpret_cast<float4*>(&lv[r][c4]) = vr[k];
        }
    };

    loadA(0);
    storeA();
    __syncthreads();
    for (int it = 0; it < Sc / 32; ++it) {
        if (it + 1 < Sc / 32) loadA(it + 1);
        #pragma unroll 8
        for (int r = 0; r < 32; ++r) {
            const float4 k4 = *reinterpret_cast<const float4*>(&lk[r][d0]);
            const float4 v4 = *reinterpret_cast<const float4*>(&lv[r][m0]);
            const float kk[4] = {k4.x, k4.y, k4.z, k4.w};
            const float vv[4] = {v4.x, v4.y, v4.z, v4.w};
            ks[0] += kk[0]; ks[1] += kk[1]; ks[2] += kk[2]; ks[3] += kk[3];
            #pragma unroll
            for (int i = 0; i < 4; ++i)
                #pragma unroll
                for (int j = 0; j < 4; ++j)
                    acc[i][j] += kk[i] * vv[j];
        }
        __syncthreads();
        if (it + 1 < Sc / 32) storeA();
        __syncthreads();
    }

    #pragma unroll
    for (int i = 0; i < 4; ++i) {
        float4 w;
        w.x = acc[i][0]; w.y = acc[i][1]; w.z = acc[i][2]; w.w = acc[i][3];
        *reinterpret_cast<float4*>(&kvt[d0 + i][m0]) = w;
    }
    if (ty == 0) {
        #pragma unroll
        for (int i = 0; i < 4; ++i) ksm[d0 + i] = ks[i];
    }
    __syncthreads();

    float4 qr[4];
    auto loadB = [&](int it) {
        const int l0 = it * 64;
        #pragma unroll
        for (int k = 0; k < 4; ++k) {
            const int r = r0 + 16 * k;
            const size_t off = rowbase + (size_t)(l0 + r) * HD + c4;
            qr[k] = *reinterpret_cast<const float4*>(Qg + off);
        }
    };
    const int swzw = (tx & 7) << 2;
    auto storeB = [&]() {
        #pragma unroll
        for (int k = 0; k < 4; ++k) {
            const int r = r0 + 16 * k;
            const int lidx = r ^ swzw;
            qt[c4 + 0][lidx] = elup1(qr[k].x);
            qt[c4 + 1][lidx] = elup1(qr[k].y);
            qt[c4 + 2][lidx] = elup1(qr[k].z);
            qt[c4 + 3][lidx] = elup1(qr[k].w);
        }
    };

    loadB(0);
    storeB();
    __syncthreads();
    for (int it = 0; it < Lc / 64; ++it) {
        if (it + 1 < Lc / 64) loadB(it + 1);
        float accB[4][4] = {{0.f,0.f,0.f,0.f},{0.f,0.f,0.f,0.f},{0.f,0.f,0.f,0.f},{0.f,0.f,0.f,0.f}};
        float za[4] = {0.f, 0.f, 0.f, 0.f};
        #pragma unroll 8
        for (int d = 0; d < Dc; ++d) {
            const int swz = ((d >> 2) & 7) << 2;
            const float4 q4  = *reinterpret_cast<const float4*>(&qt[d][(4 * ty) ^ swz]);
            const float4 kv4 = *reinterpret_cast<const float4*>(&kvt[d][4 * tx]);
            const float kd = ksm[d];
            const float qq[4] = {q4.x, q4.y, q4.z, q4.w};
            const float kv[4] = {kv4.x, kv4.y, kv4.z, kv4.w};
            #pragma unroll
            for (int i = 0; i < 4; ++i) {
                za[i] += qq[i] * kd;
                #pragma unroll
                for (int j = 0; j < 4; ++j)
                    accB[i][j] += qq[i] * kv[j];
            }
        }
        const int l0 = it * 64;
        const size_t obase = (size_t)bn * Lc * HD + (size_t)h * Mc;
        #pragma unroll
        for (int i = 0; i < 4; ++i) {
            const int l = l0 + 4 * ty + i;
            const float z = 1.0f / (za[i] + EPSF);
            float4 o;
            o.x = accB[i][0] * z; o.y = accB[i][1] * z;
            o.z = accB[i][2] * z; o.w = accB[i][3] * z;
            *reinterpret_cast<float4*>(Og + obase + (size_t)l * HD + 4 * tx) = o;
        }
        __syncthreads();
        if (it + 1 < Lc / 64) storeB();
        __syncthreads();
    }
}

extern "C" void kernel_launch(void* const* d_in, const int* in_sizes, int n_in,
                              void* d_out, int out_size, void* d_ws, size_t ws_size,
                              hipStream_t stream) {
    const float* Qg = (const float*)d_in[0];
    const float* Kg = (const float*)d_in[1];
    const float* Vg = (const float*)d_in[2];
    const float* Mg = (const float*)d_in[3];
    float* Og = (float*)d_out;

    const size_t need = (size_t)GROUPS * SPLITS * PARTIAL * sizeof(float);
    if (ws_size >= need) {
        float* ws = (float*)d_ws;
        hipLaunchKernelGGL(la_kv_mfma, dim3(SPLITS, GROUPS), dim3(256), 0, stream,
                           Kg, Vg, Mg, ws);
        hipLaunchKernelGGL(la_out_mfma, dim3(LSPLITS, GROUPS), dim3(256), 0, stream,
                           Qg, ws, Og);
    } else {
        hipLaunchKernelGGL(la_fused_kernel, dim3(GROUPS), dim3(256), 0, stream,
                           Qg, Kg, Vg, Mg, Og);
    }
}